// Round 1
// baseline (279.583 us; speedup 1.0000x reference)
//
#include <hip/hip_runtime.h>
#include <stdint.h>

#define LN_EPS 1e-5f
#define GN_EPS 1e-5f

// ---------------- K0: zero counts & channel sums; detect edge dtype ----------
__global__ void k_zero_detect(int* counts, float* chanS, int N,
                              const uint32_t* edge_words, int* flag) {
  int idx = blockIdx.x * blockDim.x + threadIdx.x;
  if (idx < N) counts[idx] = 0;
  if (idx < 128) chanS[idx] = 0.f;
  if (blockIdx.x == 0) {
    // Odd 32-bit words of the first 16KB: all-zero => data is int64 (high
    // words of small indices); any nonzero => data is int32.
    __shared__ uint32_t red[256];
    uint32_t v = 0;
    for (int k = 0; k < 8; ++k) {
      int w = 2 * ((int)threadIdx.x + 256 * k) + 1;  // 1..4095
      v |= edge_words[w];
    }
    red[threadIdx.x] = v;
    __syncthreads();
    for (int s = 128; s > 0; s >>= 1) {
      if ((int)threadIdx.x < s) red[threadIdx.x] |= red[threadIdx.x + s];
      __syncthreads();
    }
    if (threadIdx.x == 0) *flag = (red[0] != 0) ? 1 : 0;  // 1 => int32
  }
}

__device__ __forceinline__ int edge_at(const void* p, int is32, long long i) {
  return is32 ? ((const int*)p)[i] : (int)(((const long long*)p)[i]);
}

// ---------------- K1: histogram of dst ----------
__global__ void k_hist(const void* edges, const int* flag, int E, int* counts) {
  int e = blockIdx.x * 256 + threadIdx.x;
  if (e >= E) return;
  int f = *flag;
  int d = edge_at(edges, f, (long long)E + e);
  atomicAdd(&counts[d], 1);
}

// ---------------- K2: per-block inclusive scan ----------
__global__ void k_scanA(const int* counts, int* incl, int* partials, int N) {
  __shared__ int sh[512];
  int i = blockIdx.x * 512 + threadIdx.x;
  int v = (i < N) ? counts[i] : 0;
  sh[threadIdx.x] = v;
  __syncthreads();
  for (int s = 1; s < 512; s <<= 1) {
    int add = ((int)threadIdx.x >= s) ? sh[threadIdx.x - s] : 0;
    __syncthreads();
    sh[threadIdx.x] += add;
    __syncthreads();
  }
  if (i < N) incl[i] = sh[threadIdx.x];
  if (threadIdx.x == 511) partials[blockIdx.x] = sh[511];
}

// ---------------- K3: scan of block partials -> exclusive base ----------
__global__ void k_scanB(int* partials, int nb) {
  __shared__ int sh[128];
  int t = threadIdx.x;
  int v = (t < nb) ? partials[t] : 0;
  sh[t] = v;
  __syncthreads();
  for (int s = 1; s < 128; s <<= 1) {
    int add = (t >= s) ? sh[t - s] : 0;
    __syncthreads();
    sh[t] += add;
    __syncthreads();
  }
  if (t < nb) partials[t] = sh[t] - v;  // exclusive
}

// ---------------- K4: finalize exclusive offsets + init cursor ----------
__global__ void k_scanC(int* incl, const int* counts, const int* partials,
                        int* cursor, int N) {
  int i = blockIdx.x * 256 + threadIdx.x;
  if (i >= N) return;
  int ex = incl[i] - counts[i] + partials[i / 512];
  incl[i] = ex;       // incl array now holds exclusive start offsets
  cursor[i] = ex;
}

// ---------------- K5: bucket-scatter src indices into CSR ----------
__global__ void k_scatter(const void* edges, const int* flag, int E,
                          int* cursor, int* csr) {
  int e = blockIdx.x * 256 + threadIdx.x;
  if (e >= E) return;
  int f = *flag;
  int s = edge_at(edges, f, e);
  int d = edge_at(edges, f, (long long)E + e);
  int p = atomicAdd(&cursor[d], 1);
  csr[p] = s;
}

// ---------------- K6: gather-sum (atomic-free): h = x + sum_{src} x[src] ----
__global__ __launch_bounds__(256) void k_gather(const float4* __restrict__ x4,
                         const int* __restrict__ csr,
                         const int* __restrict__ offsets,
                         const int* __restrict__ counts,
                         float4* __restrict__ out4, int N) {
  int t = blockIdx.x * 256 + threadIdx.x;
  int g = t >> 4;    // node
  int q = t & 15;    // float4 slot within the 64-ch row
  if (g >= N) return;
  float4 acc = x4[g * 16 + q];   // self term, (1+eps)*x with eps=0
  int start = offsets[g], cnt = counts[g];
  for (int j = 0; j < cnt; ++j) {
    int s = csr[start + j];
    float4 v = x4[s * 16 + q];
    acc.x += v.x; acc.y += v.y; acc.z += v.z; acc.w += v.w;
  }
  out4[g * 16 + q] = acc;
}

// ---------------- K7: fused  y = relu(LN(in @ W^T)) ; optional stats --------
// Block = 256 threads, 64 nodes per block. W and H staged transposed in LDS
// so inner-loop reads are conflict-free ds_read_b128. Each thread computes a
// 4-node x 4-channel register tile.
template <int DO_STATS>
__global__ __launch_bounds__(256) void k_mlp(const float* __restrict__ in,
                      const float* __restrict__ Wg,
                      const float* __restrict__ lnw,
                      const float* __restrict__ lnb,
                      float* __restrict__ out, int N, float* chanS) {
  __shared__ float Wt[64 * 64];   // Wt[k][c] = W[c][k]
  __shared__ float Ht[64 * 64];   // Ht[k][n]
  __shared__ float cs1[64], cs2[64];
  const int t = threadIdx.x;
  const int node0 = blockIdx.x * 64;

  if (DO_STATS && t < 64) { cs1[t] = 0.f; cs2[t] = 0.f; }

  {  // stage W transposed: thread handles row c = t&63, k-quads
    int c = t & 63, w = t >> 6;
    #pragma unroll
    for (int r = 0; r < 4; ++r) {
      int k4 = w * 4 + 16 * r;
      float4 v = *(const float4*)&Wg[c * 64 + k4];
      Wt[(k4 + 0) * 64 + c] = v.x;
      Wt[(k4 + 1) * 64 + c] = v.y;
      Wt[(k4 + 2) * 64 + c] = v.z;
      Wt[(k4 + 3) * 64 + c] = v.w;
    }
  }
  {  // stage H transposed
    int n = t & 63, w = t >> 6;
    bool valid = (node0 + n) < N;
    #pragma unroll
    for (int r = 0; r < 4; ++r) {
      int c4 = w * 4 + 16 * r;
      float4 v = valid ? *(const float4*)&in[(long long)(node0 + n) * 64 + c4]
                       : make_float4(0.f, 0.f, 0.f, 0.f);
      Ht[(c4 + 0) * 64 + n] = v.x;
      Ht[(c4 + 1) * 64 + n] = v.y;
      Ht[(c4 + 2) * 64 + n] = v.z;
      Ht[(c4 + 3) * 64 + n] = v.w;
    }
  }
  __syncthreads();

  const int tx = t & 15;   // channel quad: channels 4*tx..4*tx+3
  const int ty = t >> 4;   // node quad:   nodes    4*ty..4*ty+3
  float acc[4][4] = {};
  #pragma unroll 8
  for (int k = 0; k < 64; ++k) {
    float4 hv = *(float4*)&Ht[k * 64 + 4 * ty];
    float4 wv = *(float4*)&Wt[k * 64 + 4 * tx];
    acc[0][0] += hv.x * wv.x; acc[0][1] += hv.x * wv.y;
    acc[0][2] += hv.x * wv.z; acc[0][3] += hv.x * wv.w;
    acc[1][0] += hv.y * wv.x; acc[1][1] += hv.y * wv.y;
    acc[1][2] += hv.y * wv.z; acc[1][3] += hv.y * wv.w;
    acc[2][0] += hv.z * wv.x; acc[2][1] += hv.z * wv.y;
    acc[2][2] += hv.z * wv.z; acc[2][3] += hv.z * wv.w;
    acc[3][0] += hv.w * wv.x; acc[3][1] += hv.w * wv.y;
    acc[3][2] += hv.w * wv.z; acc[3][3] += hv.w * wv.w;
  }

  const float4 lw = *(const float4*)&lnw[4 * tx];
  const float4 lb = *(const float4*)&lnb[4 * tx];
  float st1[4] = {0.f, 0.f, 0.f, 0.f}, st2[4] = {0.f, 0.f, 0.f, 0.f};

  #pragma unroll
  for (int j = 0; j < 4; ++j) {
    int node = node0 + 4 * ty + j;
    // LayerNorm over 64 channels = reduce across the 16 tx lanes
    float s = acc[j][0] + acc[j][1] + acc[j][2] + acc[j][3];
    #pragma unroll
    for (int m = 1; m < 16; m <<= 1) s += __shfl_xor(s, m, 16);
    float mu = s * (1.f / 64.f);
    float d0 = acc[j][0] - mu, d1 = acc[j][1] - mu;
    float d2 = acc[j][2] - mu, d3 = acc[j][3] - mu;
    float v = d0 * d0 + d1 * d1 + d2 * d2 + d3 * d3;
    #pragma unroll
    for (int m = 1; m < 16; m <<= 1) v += __shfl_xor(v, m, 16);
    float rs = rsqrtf(v * (1.f / 64.f) + LN_EPS);
    float y0 = fmaxf(d0 * rs * lw.x + lb.x, 0.f);
    float y1 = fmaxf(d1 * rs * lw.y + lb.y, 0.f);
    float y2 = fmaxf(d2 * rs * lw.z + lb.z, 0.f);
    float y3 = fmaxf(d3 * rs * lw.w + lb.w, 0.f);
    if (node < N) {
      *(float4*)&out[(long long)node * 64 + 4 * tx] = make_float4(y0, y1, y2, y3);
      if (DO_STATS) {
        st1[0] += y0; st2[0] += y0 * y0;
        st1[1] += y1; st2[1] += y1 * y1;
        st1[2] += y2; st2[2] += y2 * y2;
        st1[3] += y3; st2[3] += y3 * y3;
      }
    }
  }

  if (DO_STATS) {
    #pragma unroll
    for (int i = 0; i < 4; ++i) {
      atomicAdd(&cs1[4 * tx + i], st1[i]);
      atomicAdd(&cs2[4 * tx + i], st2[i]);
    }
    __syncthreads();
    if (t < 64) {
      atomicAdd(&chanS[t], cs1[t]);
      atomicAdd(&chanS[64 + t], cs2[t]);
    }
  }
}

// ---------------- K8: GraphNorm per-channel scale/shift ----------
__global__ void k_finalize(const float* chanS, const float* alpha,
                           const float* gnw, const float* gnb, float* ab,
                           int N) {
  int c = threadIdx.x;
  if (c >= 64) return;
  float invN = 1.f / (float)N;
  float mu = chanS[c] * invN;
  float e2 = chanS[64 + c] * invN;
  float al = alpha[c];
  float var = e2 - 2.f * al * mu * mu + al * al * mu * mu;
  float a = gnw[c] * rsqrtf(var + GN_EPS);
  float b = gnb[c] - a * al * mu;
  ab[c] = a;
  ab[64 + c] = b;
}

// ---------------- K9: out = a[c]*h + b[c] ----------
__global__ __launch_bounds__(256) void k_apply(const float4* __restrict__ h4,
                        const float* __restrict__ ab,
                        float4* __restrict__ outp, int N) {
  int idx = blockIdx.x * 256 + threadIdx.x;
  if (idx >= N * 16) return;
  int q = idx & 15;
  float4 a = *(const float4*)&ab[q * 4];
  float4 b = *(const float4*)&ab[64 + q * 4];
  float4 h = h4[idx];
  outp[idx] = make_float4(a.x * h.x + b.x, a.y * h.y + b.y,
                          a.z * h.z + b.z, a.w * h.w + b.w);
}

extern "C" void kernel_launch(void* const* d_in, const int* in_sizes, int n_in,
                              void* d_out, int out_size, void* d_ws,
                              size_t ws_size, hipStream_t stream) {
  const float* x   = (const float*)d_in[0];
  const void* edges = d_in[1];
  const float* W0   = (const float*)d_in[2];
  const float* ln0w = (const float*)d_in[3];
  const float* ln0b = (const float*)d_in[4];
  const float* W1   = (const float*)d_in[5];
  const float* ln1w = (const float*)d_in[6];
  const float* ln1b = (const float*)d_in[7];
  const float* gnw  = (const float*)d_in[8];
  const float* gnb  = (const float*)d_in[9];
  const float* gna  = (const float*)d_in[10];
  const int N = in_sizes[0] / 64;
  const int E = in_sizes[1] / 2;

  // workspace layout (~29 MB)
  float* bufA = (float*)d_ws;                  // N*64
  float* bufB = bufA + (size_t)N * 64;         // N*64
  int* csr     = (int*)(bufB + (size_t)N * 64);  // E
  int* counts  = csr + E;                        // N
  int* offsets = counts + N;                     // N (incl -> exclusive)
  int* cursor  = offsets + N;                    // N
  int* partials = cursor + N;                    // 256
  int* flag     = partials + 256;                // 1 (+pad)
  float* chanS  = (float*)(flag + 4);            // 128
  float* ab     = chanS + 128;                   // 128

  const int nbScan = (N + 511) / 512;
  const int blkN   = (N + 255) / 256;
  const int blkE   = (E + 255) / 256;
  const int blkG   = (N * 16 + 255) / 256;
  const int blkM   = (N + 63) / 64;

  k_zero_detect<<<blkN, 256, 0, stream>>>(counts, chanS, N,
                                          (const uint32_t*)edges, flag);
  k_hist<<<blkE, 256, 0, stream>>>(edges, flag, E, counts);
  k_scanA<<<nbScan, 512, 0, stream>>>(counts, offsets, partials, N);
  k_scanB<<<1, 128, 0, stream>>>(partials, nbScan);
  k_scanC<<<blkN, 256, 0, stream>>>(offsets, counts, partials, cursor, N);
  k_scatter<<<blkE, 256, 0, stream>>>(edges, flag, E, cursor, csr);
  k_gather<<<blkG, 256, 0, stream>>>((const float4*)x, csr, offsets, counts,
                                     (float4*)bufA, N);
  k_mlp<0><<<blkM, 256, 0, stream>>>(bufA, W0, ln0w, ln0b, bufB, N, chanS);
  k_mlp<1><<<blkM, 256, 0, stream>>>(bufB, W1, ln1w, ln1b, bufA, N, chanS);
  k_finalize<<<1, 64, 0, stream>>>(chanS, gna, gnw, gnb, ab, N);
  k_apply<<<blkG, 256, 0, stream>>>((const float4*)bufA, ab, (float4*)d_out, N);
}